// Round 1
// baseline (666.894 us; speedup 1.0000x reference)
//
#include <hip/hip_runtime.h>

#define GH 135
#define GW 240
#define HH 1080
#define WW 1920
#define HWPX (HH*WW)
#define NP 12
#define JT 20              // anchor blocks per WG
#define TBLK (JT+8)        // staged target blocks per dy-row (halo +-4)
#define BSTR 68            // padded dwords per staged block (64 px + 4)
#define RSTR (TBLK*BSTR+4) // dwords per dy-row = 1908
#define NTHR 192
#define NPAIR (JT*9)       // 180 (block, dy) pairs

// LDS layout (dwords): redc double[180] | Tt float[9*RSTR] | Ta float[JT*BSTR] | redk int[180]
#define LDS_DW (360 + 9*RSTR + JT*BSTR + 180)   // 19072 dw = 76288 B

__global__ void __launch_bounds__(NTHR) hbma_cost_kernel(const float* __restrict__ A,
                                                         const float* __restrict__ T,
                                                         int* __restrict__ bestidx) {
    extern __shared__ float lds[];
    double* redc = (double*)lds;
    float*  Tt   = lds + 360;
    float*  Ta   = Tt + 9*RSTR;
    int*    redk = (int*)(Ta + JT*BSTR);

    const int i   = blockIdx.x;
    const int j0  = blockIdx.y * JT;
    const int tid = threadIdx.x;

    const int b  = tid / 9;
    const int dy = tid % 9;
    const bool pairActive = (tid < NPAIR);
    const int  gi = i + dy - 4;
    const bool dyValid = pairActive && (gi >= 0) && (gi < GH);

    double acc[9];
#pragma unroll
    for (int d = 0; d < 9; ++d) acc[d] = 0.0;

    const int gy0 = (i - 4) * 8;
    const int gx0 = (j0 - 4) * 8;

    for (int q = 0; q < NP; ++q) {
        __syncthreads();
        // ---- stage target halo: 72 pixel rows x 56 float4 (=224 px) ----
        {
            const float* Tq = T + q * HWPX;
            for (int idx = tid; idx < 72 * 56; idx += NTHR) {
                const int r  = idx / 56;
                const int c4 = idx % 56;
                const int gy = gy0 + r;
                const int gx = gx0 + c4 * 4;
                if ((unsigned)gy < (unsigned)HH && (unsigned)gx < (unsigned)WW) {
                    const float4 v = *(const float4*)(Tq + gy * WW + gx);
                    const int dyr = r >> 3, y = r & 7, blk = c4 >> 1, xh = (c4 & 1) * 4;
                    *(float4*)(Tt + dyr * RSTR + blk * BSTR + y * 8 + xh) = v;
                }
            }
        }
        // ---- stage anchor tile: 8 rows x 40 float4 ----
        {
            const float* Aq = A + q * HWPX;
            for (int idx = tid; idx < 8 * 40; idx += NTHR) {
                const int r  = idx / 40;
                const int c4 = idx % 40;
                const float4 v = *(const float4*)(Aq + (i * 8 + r) * WW + j0 * 8 + c4 * 4);
                const int blk = c4 >> 1, xh = (c4 & 1) * 4;
                *(float4*)(Ta + blk * BSTR + r * 8 + xh) = v;
            }
        }
        __syncthreads();
        // ---- accumulate SSD: thread = (anchor block b, dy); 9 dx in registers ----
        if (dyValid) {
            const float* tbase = Tt + dy * RSTR + b * BSTR;
            const float* abase = Ta + b * BSTR;
#pragma unroll
            for (int y = 0; y < 8; ++y) {
                const float4 a0 = *(const float4*)(abase + y * 8);
                const float4 a1 = *(const float4*)(abase + y * 8 + 4);
#pragma unroll
                for (int dxi = 0; dxi < 9; ++dxi) {
                    const float4 t0 = *(const float4*)(tbase + dxi * BSTR + y * 8);
                    const float4 t1 = *(const float4*)(tbase + dxi * BSTR + y * 8 + 4);
                    const float d0 = a0.x - t0.x, d1 = a0.y - t0.y;
                    const float d2 = a0.z - t0.z, d3 = a0.w - t0.w;
                    const float d4 = a1.x - t1.x, d5 = a1.y - t1.y;
                    const float d6 = a1.z - t1.z, d7 = a1.w - t1.w;
                    float s = d0 * d0;
                    s = fmaf(d1, d1, s); s = fmaf(d2, d2, s); s = fmaf(d3, d3, s);
                    s = fmaf(d4, d4, s); s = fmaf(d5, d5, s); s = fmaf(d6, d6, s);
                    s = fmaf(d7, d7, s);
                    acc[dxi] += (double)s;   // fp64 accumulate: total err ~1e-6, argmin-safe
                }
            }
        }
    }
    // ---- stage 1 argmin: per-thread over dx (ascending -> first-k on ties) ----
    double bc = 1e300; int bk = -1;
    if (dyValid) {
#pragma unroll
        for (int dxi = 0; dxi < 9; ++dxi) {
            const int gj = j0 + b + dxi - 4;
            if (gj >= 0 && gj < GW && acc[dxi] < bc) { bc = acc[dxi]; bk = dy * 9 + dxi; }
        }
    }
    if (pairActive) { redc[tid] = bc; redk[tid] = bk; }
    __syncthreads();
    // ---- stage 2 argmin: over dy (ascending, strict <) ----
    if (tid < JT) {
        double c = 1e300; int k = -1;
#pragma unroll
        for (int dyi = 0; dyi < 9; ++dyi) {
            const int t = tid * 9 + dyi;
            if (redc[t] < c) { c = redc[t]; k = redk[t]; }
        }
        const int dyi = k / 9, dxi = k % 9;
        const int bi = i + dyi - 4;
        const int bj = j0 + tid + dxi - 4;
        bestidx[i * GW + j0 + tid] = (bi << 8) | bj;   // bi<135, bj<240 both fit
    }
}

__global__ void __launch_bounds__(256) hbma_gather_kernel(const float* __restrict__ A,
                                                          const int* __restrict__ bestidx,
                                                          float* __restrict__ out) {
    const int tid = blockIdx.x * 256 + threadIdx.x;
    const int q   = tid / (HWPX / 4);
    const int rem = tid % (HWPX / 4);
    const int py  = rem / (WW / 4);
    const int c4  = rem % (WW / 4);
    const int i = py >> 3, y = py & 7;
    const int j = c4 >> 1, xh = (c4 & 1) * 4;
    const int idx = bestidx[i * GW + j];
    const int bi = idx >> 8, bj = idx & 255;
    const float4 v = *(const float4*)(A + q * HWPX + (bi * 8 + y) * WW + bj * 8 + xh);
    *(float4*)(out + q * HWPX + py * WW + c4 * 4) = v;
}

extern "C" void kernel_launch(void* const* d_in, const int* in_sizes, int n_in,
                              void* d_out, int out_size, void* d_ws, size_t ws_size,
                              hipStream_t stream) {
    const float* A = (const float*)d_in[0];   // anchor_frame
    const float* T = (const float*)d_in[1];   // target_frame
    float* out = (float*)d_out;
    int* bestidx = (int*)d_ws;                // 32400 ints

    hipFuncSetAttribute((const void*)hbma_cost_kernel,
                        hipFuncAttributeMaxDynamicSharedMemorySize, LDS_DW * 4);

    dim3 g1(GH, GW / JT);   // x = i (consecutive WGs share 8/9 of target halo in L2)
    hipLaunchKernelGGL(hbma_cost_kernel, g1, dim3(NTHR), LDS_DW * 4, stream, A, T, bestidx);

    const int total4 = (NP * HWPX) / 4;       // 6,220,800 float4s
    hipLaunchKernelGGL(hbma_gather_kernel, dim3(total4 / 256), dim3(256), 0, stream,
                       A, bestidx, out);
}

// Round 2
// 639.206 us; speedup vs baseline: 1.0433x; 1.0433x over previous
//
#include <hip/hip_runtime.h>

#define GH 135
#define GW 240
#define HH 1080
#define WW 1920
#define HWPX (HH*WW)
#define NP 12
#define JT 20              // anchor blocks per WG
#define TBLK (JT+8)        // staged target blocks per dy-row (halo +-4)
#define BSTR 68            // padded dwords per staged block (64 px + 4)
#define RSTR (TBLK*BSTR+4) // dwords per dy-row = 1908
#define NTHR 192
#define NPAIR (JT*9)       // 180 (block, dy) pairs

// LDS layout (dwords): redc double[180] | Tt float[9*RSTR] | Ta float[JT*BSTR] | redk int[180]
#define LDS_DW (360 + 9*RSTR + JT*BSTR + 180)   // 19072 dw = 76288 B

// __launch_bounds__(.,1): LDS caps us at 2 WG/CU (1.5 waves/SIMD) regardless;
// give the register allocator the full VGPR budget so acc[9] (fp64) stays in
// registers. Round-1 evidence of spills: VGPR_Count=32 + WRITE_SIZE=152MB of
// scratch traffic vs 130KB of legitimate stores.
__global__ void __launch_bounds__(NTHR, 1) hbma_cost_kernel(const float* __restrict__ A,
                                                            const float* __restrict__ T,
                                                            int* __restrict__ bestidx) {
    extern __shared__ float lds[];
    double* redc = (double*)lds;
    float*  Tt   = lds + 360;
    float*  Ta   = Tt + 9*RSTR;
    int*    redk = (int*)(Ta + JT*BSTR);

    const int i   = blockIdx.x;
    const int j0  = blockIdx.y * JT;
    const int tid = threadIdx.x;

    const int b  = tid / 9;
    const int dy = tid % 9;
    const bool pairActive = (tid < NPAIR);
    const int  gi = i + dy - 4;
    const bool dyValid = pairActive && (gi >= 0) && (gi < GH);

    double acc[9];
#pragma unroll
    for (int d = 0; d < 9; ++d) acc[d] = 0.0;

    const int gy0 = (i - 4) * 8;
    const int gx0 = (j0 - 4) * 8;

    for (int q = 0; q < NP; ++q) {
        __syncthreads();
        // ---- stage target halo: 72 pixel rows x 56 float4 (=224 px) ----
        {
            const float* Tq = T + q * HWPX;
            for (int idx = tid; idx < 72 * 56; idx += NTHR) {
                const int r  = idx / 56;
                const int c4 = idx % 56;
                const int gy = gy0 + r;
                const int gx = gx0 + c4 * 4;
                if ((unsigned)gy < (unsigned)HH && (unsigned)gx < (unsigned)WW) {
                    const float4 v = *(const float4*)(Tq + gy * WW + gx);
                    const int dyr = r >> 3, y = r & 7, blk = c4 >> 1, xh = (c4 & 1) * 4;
                    *(float4*)(Tt + dyr * RSTR + blk * BSTR + y * 8 + xh) = v;
                }
            }
        }
        // ---- stage anchor tile: 8 rows x 40 float4 ----
        {
            const float* Aq = A + q * HWPX;
            for (int idx = tid; idx < 8 * 40; idx += NTHR) {
                const int r  = idx / 40;
                const int c4 = idx % 40;
                const float4 v = *(const float4*)(Aq + (i * 8 + r) * WW + j0 * 8 + c4 * 4);
                const int blk = c4 >> 1, xh = (c4 & 1) * 4;
                *(float4*)(Ta + blk * BSTR + r * 8 + xh) = v;
            }
        }
        __syncthreads();
        // ---- accumulate SSD: thread = (anchor block b, dy); 9 dx in registers ----
        if (dyValid) {
            const float* tbase = Tt + dy * RSTR + b * BSTR;
            const float* abase = Ta + b * BSTR;
#pragma unroll
            for (int y = 0; y < 8; ++y) {
                const float4 a0 = *(const float4*)(abase + y * 8);
                const float4 a1 = *(const float4*)(abase + y * 8 + 4);
                // issue all 18 target b128 reads as one block -> deep lgkmcnt
                // pipelining; compute afterwards from registers (ILP covers
                // LDS latency at our 6-waves/CU occupancy).
                float4 t0[9], t1[9];
#pragma unroll
                for (int dxi = 0; dxi < 9; ++dxi) {
                    t0[dxi] = *(const float4*)(tbase + dxi * BSTR + y * 8);
                    t1[dxi] = *(const float4*)(tbase + dxi * BSTR + y * 8 + 4);
                }
#pragma unroll
                for (int dxi = 0; dxi < 9; ++dxi) {
                    const float d0 = a0.x - t0[dxi].x, d1 = a0.y - t0[dxi].y;
                    const float d2 = a0.z - t0[dxi].z, d3 = a0.w - t0[dxi].w;
                    const float d4 = a1.x - t1[dxi].x, d5 = a1.y - t1[dxi].y;
                    const float d6 = a1.z - t1[dxi].z, d7 = a1.w - t1[dxi].w;
                    float s = d0 * d0;
                    s = fmaf(d1, d1, s); s = fmaf(d2, d2, s); s = fmaf(d3, d3, s);
                    s = fmaf(d4, d4, s); s = fmaf(d5, d5, s); s = fmaf(d6, d6, s);
                    s = fmaf(d7, d7, s);
                    acc[dxi] += (double)s;   // fp64 accumulate: total err ~1e-6, argmin-safe
                }
            }
        }
    }
    // ---- stage 1 argmin: per-thread over dx (ascending -> first-k on ties) ----
    double bc = 1e300; int bk = -1;
    if (dyValid) {
#pragma unroll
        for (int dxi = 0; dxi < 9; ++dxi) {
            const int gj = j0 + b + dxi - 4;
            if (gj >= 0 && gj < GW && acc[dxi] < bc) { bc = acc[dxi]; bk = dy * 9 + dxi; }
        }
    }
    if (pairActive) { redc[tid] = bc; redk[tid] = bk; }
    __syncthreads();
    // ---- stage 2 argmin: over dy (ascending, strict <) ----
    if (tid < JT) {
        double c = 1e300; int k = -1;
#pragma unroll
        for (int dyi = 0; dyi < 9; ++dyi) {
            const int t = tid * 9 + dyi;
            if (redc[t] < c) { c = redc[t]; k = redk[t]; }
        }
        const int dyi = k / 9, dxi = k % 9;
        const int bi = i + dyi - 4;
        const int bj = j0 + tid + dxi - 4;
        bestidx[i * GW + j0 + tid] = (bi << 8) | bj;   // bi<135, bj<240 both fit
    }
}

__global__ void __launch_bounds__(256) hbma_gather_kernel(const float* __restrict__ A,
                                                          const int* __restrict__ bestidx,
                                                          float* __restrict__ out) {
    const int tid = blockIdx.x * 256 + threadIdx.x;
    const int q   = tid / (HWPX / 4);
    const int rem = tid % (HWPX / 4);
    const int py  = rem / (WW / 4);
    const int c4  = rem % (WW / 4);
    const int i = py >> 3, y = py & 7;
    const int j = c4 >> 1, xh = (c4 & 1) * 4;
    const int idx = bestidx[i * GW + j];
    const int bi = idx >> 8, bj = idx & 255;
    const float4 v = *(const float4*)(A + q * HWPX + (bi * 8 + y) * WW + bj * 8 + xh);
    *(float4*)(out + q * HWPX + py * WW + c4 * 4) = v;
}

extern "C" void kernel_launch(void* const* d_in, const int* in_sizes, int n_in,
                              void* d_out, int out_size, void* d_ws, size_t ws_size,
                              hipStream_t stream) {
    const float* A = (const float*)d_in[0];   // anchor_frame
    const float* T = (const float*)d_in[1];   // target_frame
    float* out = (float*)d_out;
    int* bestidx = (int*)d_ws;                // 32400 ints

    hipFuncSetAttribute((const void*)hbma_cost_kernel,
                        hipFuncAttributeMaxDynamicSharedMemorySize, LDS_DW * 4);

    dim3 g1(GH, GW / JT);   // x = i (consecutive WGs share 8/9 of target halo in L2)
    hipLaunchKernelGGL(hbma_cost_kernel, g1, dim3(NTHR), LDS_DW * 4, stream, A, T, bestidx);

    const int total4 = (NP * HWPX) / 4;       // 6,220,800 float4s
    hipLaunchKernelGGL(hbma_gather_kernel, dim3(total4 / 256), dim3(256), 0, stream,
                       A, bestidx, out);
}

// Round 3
// 382.197 us; speedup vs baseline: 1.7449x; 1.6725x over previous
//
#include <hip/hip_runtime.h>

#define GH 135
#define GW 240
#define HH 1080
#define WW 1920
#define HWPX (HH*WW)
#define NP 12
#define JT 24              // anchor blocks per WG
#define NBG 12             // anchor PAIRS per WG (2 adjacent blocks/thread)
#define HALO 32            // JT+8 staged target blocks per dy-row
#define NJT 10             // GW/JT
#define DSTR (HALO*64+16)  // 2064 dw per dy-row; 2064%32==16 separates dy bank-groups
#define NTHR 256
#define NACT 216           // 12 bg * 9 dy * 2 yh
#define TT_DW (9*DSTR)     // 18576 dw = 74304 B -> 2 WG/CU

// 8-px fp32 chain + f64 accumulate (argmin-exact vs np reference, proven r1/r2)
#define CHAIN(AV0, AV1, T0, T1, ACC) do { \
    float _d = (AV0).x - (T0).x; float _s = _d*_d; \
    _d = (AV0).y - (T0).y; _s = fmaf(_d,_d,_s); \
    _d = (AV0).z - (T0).z; _s = fmaf(_d,_d,_s); \
    _d = (AV0).w - (T0).w; _s = fmaf(_d,_d,_s); \
    _d = (AV1).x - (T1).x; _s = fmaf(_d,_d,_s); \
    _d = (AV1).y - (T1).y; _s = fmaf(_d,_d,_s); \
    _d = (AV1).z - (T1).z; _s = fmaf(_d,_d,_s); \
    _d = (AV1).w - (T1).w; _s = fmaf(_d,_d,_s); \
    (ACC) += (double)_s; } while(0)

__global__ void __launch_bounds__(NTHR, 2)
hbma_cost_kernel(const float* __restrict__ A, const float* __restrict__ T,
                 int* __restrict__ bestidx) {
    extern __shared__ float lds[];
    float* Tt = lds;

    // XCD-bijective swizzle (m204): per-XCD consecutive WGs get consecutive i
    const int nwg = GH * NJT, qq = nwg / 8, rr = nwg % 8;   // 1350, 168, 6
    const int lin = blockIdx.x;
    const int xcd = lin & 7, pos = lin >> 3;
    const int g = (xcd < rr) ? xcd * (qq + 1) + pos
                             : rr * (qq + 1) + (xcd - rr) * qq + pos;
    const int i  = g % GH;
    const int j0 = (g / GH) * JT;

    const int tid = threadIdx.x;
    const int dy  = tid / 24;          // 0..8 for active threads
    const int rem = tid % 24;
    const int bg  = rem >> 1;          // 0..11 (anchor pair)
    const int yh  = rem & 1;           // y-half: rows 4*yh..4*yh+3
    const bool act = (tid < NACT);
    const int  gi = i + dy - 4;
    const bool dyValid = act && (gi >= 0) && (gi < GH);

    // per-p-pair XOR swizzle values: block w=2bg+p -> xv = 4*((w>>1)&7) = 4*((bg+(p>>1))&7)
    int xvv[5];
#pragma unroll
    for (int h = 0; h < 5; ++h) xvv[h] = ((bg + h) & 7) * 4;

    double acc0[9], acc1[9];
#pragma unroll
    for (int d = 0; d < 9; ++d) { acc0[d] = 0.0; acc1[d] = 0.0; }

    const int gy0 = (i - 4) * 8;
    const int gx0 = (j0 - 4) * 8;

    for (int q = 0; q < NP; ++q) {
        const float* Tq = T + q * HWPX;
        const float* Aq = A + q * HWPX;
        __syncthreads();               // prev compute done before LDS overwrite
        // ---- stage target halo: 72 rows x 64 float4, XOR-swizzled layout ----
#pragma unroll
        for (int it = 0; it < 72 * 64; it += NTHR) {
            const int idx = it + tid;
            const int r = idx >> 6, c4 = idx & 63;
            const int gy = gy0 + r, gx = gx0 + c4 * 4;
            if ((unsigned)gy < (unsigned)HH && (unsigned)gx < (unsigned)WW) {
                const float4 v = *(const float4*)(Tq + (size_t)gy * WW + gx);
                const int dyr = r >> 3, y = r & 7, blk = c4 >> 1, xh = (c4 & 1) * 4;
                const int xv = ((c4 >> 2) & 7) * 4;    // 4*((blk>>1)&7)
                *(float4*)(Tt + dyr * DSTR + blk * 64 + ((y * 8 + xh) ^ xv)) = v;
            }
        }
        // ---- anchor rows -> registers (global, L1/L2-hot across dy/yh redundancy) ----
        float4 ar[2][4][2];
        if (act) {
#pragma unroll
            for (int a2 = 0; a2 < 2; ++a2) {
                const float* ap = Aq + (size_t)(j0 + 2 * bg + a2) * 8;
#pragma unroll
                for (int yi = 0; yi < 4; ++yi) {
                    const float* row = ap + (size_t)(i * 8 + yh * 4 + yi) * WW;
                    ar[a2][yi][0] = *(const float4*)(row);
                    ar[a2][yi][1] = *(const float4*)(row + 4);
                }
            }
        }
        __syncthreads();
        // ---- SSD: sliding 10-block window serves 2 anchors x 9 dx ----
        if (dyValid) {
            const float* tb = Tt + dy * DSTR + (2 * bg) * 64 + yh * 32;
#pragma unroll
            for (int yi = 0; yi < 4; ++yi) {
#pragma unroll
                for (int p = 0; p < 10; ++p) {
                    const int xv = xvv[p >> 1];
                    const float4 t0 = *(const float4*)(tb + p * 64 + ((yi * 8) ^ xv));
                    const float4 t1 = *(const float4*)(tb + p * 64 + ((yi * 8 + 4) ^ xv));
                    if (p < 9) CHAIN(ar[0][yi][0], ar[0][yi][1], t0, t1, acc0[p]);
                    if (p > 0) CHAIN(ar[1][yi][0], ar[1][yi][1], t0, t1, acc1[p - 1]);
                }
            }
        }
    }
    // ---- y-half merge via LDS (aliases Tt, barrier-protected) ----
    __syncthreads();
    double* yred = (double*)lds;                    // 108*18 f64 = 3888 dw
    const int pairId = dy * NBG + bg;
    if (act && yh == 1) {
        double* d = yred + pairId * 18;
#pragma unroll
        for (int k = 0; k < 9; ++k) { d[k] = acc0[k]; d[9 + k] = acc1[k]; }
    }
    __syncthreads();
    double* redc = (double*)(lds + 8192);           // 216 f64
    int*    redk = (int*)(lds + 8192 + 432);        // 216 int
    if (act && yh == 0) {
        const double* d = yred + pairId * 18;
#pragma unroll
        for (int k = 0; k < 9; ++k) { acc0[k] += d[k]; acc1[k] += d[9 + k]; }
        // stage-1 argmin over dx (ascending, strict < -> first-k ties)
#pragma unroll
        for (int a2 = 0; a2 < 2; ++a2) {
            double bc = 1e300; int bk = -1;
            const int jb = j0 + 2 * bg + a2;
#pragma unroll
            for (int dxi = 0; dxi < 9; ++dxi) {
                const int gj = jb + dxi - 4;
                const double c = a2 ? acc1[dxi] : acc0[dxi];
                if (dyValid && gj >= 0 && gj < GW && c < bc) { bc = c; bk = dy * 9 + dxi; }
            }
            redc[dy * JT + 2 * bg + a2] = bc;
            redk[dy * JT + 2 * bg + a2] = bk;
        }
    }
    __syncthreads();
    // ---- stage-2 argmin over dy (ascending, strict <) ----
    if (tid < JT) {
        double c = 1e300; int k = -1;
#pragma unroll
        for (int dyi = 0; dyi < 9; ++dyi) {
            const double v = redc[dyi * JT + tid];
            if (v < c) { c = v; k = redk[dyi * JT + tid]; }
        }
        const int dyi = k / 9, dxi = k % 9;
        const int bi = i + dyi - 4;
        const int bj = j0 + tid + dxi - 4;
        bestidx[i * GW + j0 + tid] = (bi << 8) | bj;
    }
}

__global__ void __launch_bounds__(256) hbma_gather_kernel(const float* __restrict__ A,
                                                          const int* __restrict__ bestidx,
                                                          float* __restrict__ out) {
    const int tid = blockIdx.x * 256 + threadIdx.x;
    const int q   = tid / (HWPX / 4);
    const int rem = tid % (HWPX / 4);
    const int py  = rem / (WW / 4);
    const int c4  = rem % (WW / 4);
    const int i = py >> 3, y = py & 7;
    const int j = c4 >> 1, xh = (c4 & 1) * 4;
    const int idx = bestidx[i * GW + j];
    const int bi = idx >> 8, bj = idx & 255;
    const float4 v = *(const float4*)(A + (size_t)q * HWPX + (size_t)(bi * 8 + y) * WW + bj * 8 + xh);
    *(float4*)(out + (size_t)q * HWPX + (size_t)py * WW + c4 * 4) = v;
}

extern "C" void kernel_launch(void* const* d_in, const int* in_sizes, int n_in,
                              void* d_out, int out_size, void* d_ws, size_t ws_size,
                              hipStream_t stream) {
    const float* A = (const float*)d_in[0];
    const float* T = (const float*)d_in[1];
    float* out = (float*)d_out;
    int* bestidx = (int*)d_ws;

    hipFuncSetAttribute((const void*)hbma_cost_kernel,
                        hipFuncAttributeMaxDynamicSharedMemorySize, TT_DW * 4);

    hipLaunchKernelGGL(hbma_cost_kernel, dim3(GH * NJT), dim3(NTHR), TT_DW * 4, stream,
                       A, T, bestidx);

    const int total4 = (NP * HWPX) / 4;
    hipLaunchKernelGGL(hbma_gather_kernel, dim3(total4 / 256), dim3(256), 0, stream,
                       A, bestidx, out);
}

// Round 4
// 301.474 us; speedup vs baseline: 2.2121x; 1.2678x over previous
//
#include <hip/hip_runtime.h>

#define GH 135
#define GW 240
#define HH 1080
#define WW 1920
#define HWPX (HH*WW)
#define NP 12
#define IT 2               // anchor block-rows per WG (i-strip)
#define JT 12              // anchor blocks (j) per WG
#define NBG 6              // anchor pairs per it-row
#define NIG 68             // ceil(GH/IT)
#define NJG 20             // GW/JT
#define TROWS (IT+8)       // 10 staged target block-rows
#define TBLK (JT+8)        // 20 staged target blocks per dy-row
#define DSTR (TBLK*64+4)   // 1284 dw: 16B-aligned, dr*1284 %32 = 4*dr (8-way row spread)
#define NTHR 256
#define NACT 216           // 9 dy * (2 it * 6 bg * 2 yh)
#define TT_DW (TROWS*DSTR) // 12840 dw = 51360 B -> 3 WG/CU (12 waves)
#define NWG (NIG*NJG)      // 1360 = 8*170 (XCD-exact)

// 8-px fp32 chain + f64 accumulate (argmin-exact vs np reference, proven r1-r3)
#define CHAIN(AV0, AV1, T0, T1, ACC) do { \
    float _d = (AV0).x - (T0).x; float _s = _d*_d; \
    _d = (AV0).y - (T0).y; _s = fmaf(_d,_d,_s); \
    _d = (AV0).z - (T0).z; _s = fmaf(_d,_d,_s); \
    _d = (AV0).w - (T0).w; _s = fmaf(_d,_d,_s); \
    _d = (AV1).x - (T1).x; _s = fmaf(_d,_d,_s); \
    _d = (AV1).y - (T1).y; _s = fmaf(_d,_d,_s); \
    _d = (AV1).z - (T1).z; _s = fmaf(_d,_d,_s); \
    _d = (AV1).w - (T1).w; _s = fmaf(_d,_d,_s); \
    (ACC) += (double)_s; } while(0)

__global__ void __launch_bounds__(NTHR, 3)
hbma_cost_kernel(const float* __restrict__ A, const float* __restrict__ T,
                 int* __restrict__ bestidx) {
    extern __shared__ float lds[];
    float* Tt = lds;

    // XCD swizzle: 1360 WGs = 8 XCDs x 170; per-XCD consecutive pos -> consecutive ig
    const int lin = blockIdx.x;
    const int g   = (lin & 7) * (NWG / 8) + (lin >> 3);
    const int ig  = g % NIG, jg = g / NIG;
    const int i0  = ig * IT;
    const int j0  = jg * JT;

    const int tid = threadIdx.x;
    const int dy  = tid / 24;          // 0..8
    const int rem = tid % 24;
    const int it  = rem / 12;          // 0..1
    const int r2  = rem % 12;
    const int bg  = r2 >> 1;           // 0..5 (anchor pair)
    const int yh  = r2 & 1;            // y-half
    const bool act = (tid < NACT);
    const int i   = i0 + it;           // anchor row (may be GH for last strip)
    const int gi  = i + dy - 4;
    const bool dyValid = act && (i < GH) && (gi >= 0) && (gi < GH);
    const int dr  = it + dy;           // staged row index 0..9

    int xvv[5];                        // xv for p-pair h: 4*(((2bg+p)>>1)&7), p>>1==h
#pragma unroll
    for (int h = 0; h < 5; ++h) xvv[h] = ((bg + h) & 7) * 4;

    double acc0[9], acc1[9];
#pragma unroll
    for (int d = 0; d < 9; ++d) { acc0[d] = 0.0; acc1[d] = 0.0; }

    const int gy0 = (i0 - 4) * 8;
    const int gx0 = (j0 - 4) * 8;

    for (int q = 0; q < NP; ++q) {
        const float* Tq = T + (size_t)q * HWPX;
        const float* Aq = A + (size_t)q * HWPX;
        __syncthreads();               // prev compute done before LDS overwrite
        // ---- stage target halo: 80 pixel rows x 40 float4, XOR-swizzled ----
        for (int idx = tid; idx < 80 * 40; idx += NTHR) {
            const int r = idx / 40, c4 = idx % 40;
            const int gy = gy0 + r, gx = gx0 + c4 * 4;
            if ((unsigned)gy < (unsigned)HH && (unsigned)gx < (unsigned)WW) {
                const float4 v = *(const float4*)(Tq + (size_t)gy * WW + gx);
                const int dyr = r >> 3, y = r & 7, blk = c4 >> 1, xh = (c4 & 1) * 4;
                const int xv = ((c4 >> 2) & 7) * 4;    // 4*((blk>>1)&7)
                *(float4*)(Tt + dyr * DSTR + blk * 64 + ((y * 8 + xh) ^ xv)) = v;
            }
        }
        // ---- anchor rows -> registers (global; 9x dy-redundant -> L1-hot) ----
        float4 ar[2][4][2];
        if (act && i < GH) {
#pragma unroll
            for (int a2 = 0; a2 < 2; ++a2) {
                const float* ap = Aq + (size_t)(j0 + 2 * bg + a2) * 8;
#pragma unroll
                for (int yi = 0; yi < 4; ++yi) {
                    const float* row = ap + (size_t)(i * 8 + yh * 4 + yi) * WW;
                    ar[a2][yi][0] = *(const float4*)(row);
                    ar[a2][yi][1] = *(const float4*)(row + 4);
                }
            }
        }
        __syncthreads();
        // ---- SSD: sliding 10-block window serves 2 anchors x 9 dx ----
        if (dyValid) {
            const float* tb = Tt + dr * DSTR + (2 * bg) * 64 + yh * 32;
#pragma unroll
            for (int yi = 0; yi < 4; ++yi) {
#pragma unroll
                for (int ph = 0; ph < 2; ++ph) {       // p-chunks of 5: 10-deep ds ILP
                    float4 tw0[5], tw1[5];
#pragma unroll
                    for (int pp = 0; pp < 5; ++pp) {
                        const int p  = ph * 5 + pp;
                        const int xv = xvv[p >> 1];
                        tw0[pp] = *(const float4*)(tb + p * 64 + ((yi * 8) ^ xv));
                        tw1[pp] = *(const float4*)(tb + p * 64 + ((yi * 8 + 4) ^ xv));
                    }
#pragma unroll
                    for (int pp = 0; pp < 5; ++pp) {
                        const int p = ph * 5 + pp;
                        if (p < 9) CHAIN(ar[0][yi][0], ar[0][yi][1], tw0[pp], tw1[pp], acc0[p]);
                        if (p > 0) CHAIN(ar[1][yi][0], ar[1][yi][1], tw0[pp], tw1[pp], acc1[p - 1]);
                    }
                }
            }
        }
    }
    // ---- y-half merge via LDS (aliases Tt, barrier-protected) ----
    __syncthreads();
    double* yred = (double*)lds;                     // 108 pairs * 18 f64 = 3888 dw
    const int pairId = (it * NBG + bg) * 9 + dy;
    if (act && yh == 1) {
        double* d = yred + pairId * 18;
#pragma unroll
        for (int k = 0; k < 9; ++k) { d[k] = acc0[k]; d[9 + k] = acc1[k]; }
    }
    __syncthreads();
    double* redc = (double*)(lds + 8192);            // 216 f64 = 432 dw
    int*    redk = (int*)(lds + 8192 + 432);         // 216 int
    if (act && yh == 0) {
        const double* d = yred + pairId * 18;
#pragma unroll
        for (int k = 0; k < 9; ++k) { acc0[k] += d[k]; acc1[k] += d[9 + k]; }
        // stage-1 argmin over dx (ascending, strict < -> first-k ties)
#pragma unroll
        for (int a2 = 0; a2 < 2; ++a2) {
            double bc = 1e300; int bk = -1;
            const int jb = j0 + 2 * bg + a2;
#pragma unroll
            for (int dxi = 0; dxi < 9; ++dxi) {
                const int gj = jb + dxi - 4;
                const double c = a2 ? acc1[dxi] : acc0[dxi];
                if (dyValid && gj >= 0 && gj < GW && c < bc) { bc = c; bk = dy * 9 + dxi; }
            }
            redc[(it * 9 + dy) * JT + 2 * bg + a2] = bc;
            redk[(it * 9 + dy) * JT + 2 * bg + a2] = bk;
        }
    }
    __syncthreads();
    // ---- stage-2 argmin over dy (ascending, strict <) ----
    if (tid < IT * JT) {
        const int it2 = tid / JT, jt = tid % JT;
        if (i0 + it2 < GH) {
            double c = 1e300; int k = -1;
#pragma unroll
            for (int dyi = 0; dyi < 9; ++dyi) {
                const double v = redc[(it2 * 9 + dyi) * JT + jt];
                if (v < c) { c = v; k = redk[(it2 * 9 + dyi) * JT + jt]; }
            }
            const int dyi = k / 9, dxi = k % 9;
            const int bi = i0 + it2 + dyi - 4;
            const int bj = j0 + jt + dxi - 4;
            bestidx[(i0 + it2) * GW + j0 + jt] = (bi << 8) | bj;
        }
    }
}

__global__ void __launch_bounds__(256) hbma_gather_kernel(const float* __restrict__ A,
                                                          const int* __restrict__ bestidx,
                                                          float* __restrict__ out) {
    const int tid = blockIdx.x * 256 + threadIdx.x;
    const int q   = tid / (HWPX / 4);
    const int rem = tid % (HWPX / 4);
    const int py  = rem / (WW / 4);
    const int c4  = rem % (WW / 4);
    const int i = py >> 3, y = py & 7;
    const int j = c4 >> 1, xh = (c4 & 1) * 4;
    const int idx = bestidx[i * GW + j];
    const int bi = idx >> 8, bj = idx & 255;
    const float4 v = *(const float4*)(A + (size_t)q * HWPX + (size_t)(bi * 8 + y) * WW + bj * 8 + xh);
    *(float4*)(out + (size_t)q * HWPX + (size_t)py * WW + c4 * 4) = v;
}

extern "C" void kernel_launch(void* const* d_in, const int* in_sizes, int n_in,
                              void* d_out, int out_size, void* d_ws, size_t ws_size,
                              hipStream_t stream) {
    const float* A = (const float*)d_in[0];
    const float* T = (const float*)d_in[1];
    float* out = (float*)d_out;
    int* bestidx = (int*)d_ws;

    hipFuncSetAttribute((const void*)hbma_cost_kernel,
                        hipFuncAttributeMaxDynamicSharedMemorySize, TT_DW * 4);

    hipLaunchKernelGGL(hbma_cost_kernel, dim3(NWG), dim3(NTHR), TT_DW * 4, stream,
                       A, T, bestidx);

    const int total4 = (NP * HWPX) / 4;
    hipLaunchKernelGGL(hbma_gather_kernel, dim3(total4 / 256), dim3(256), 0, stream,
                       A, bestidx, out);
}

// Round 5
// 297.268 us; speedup vs baseline: 2.2434x; 1.0141x over previous
//
#include <hip/hip_runtime.h>

#define GH 135
#define GW 240
#define HH 1080
#define WW 1920
#define HWPX (HH*WW)
#define NP 12
#define IT 2               // anchor block-rows per WG (i-strip)
#define JT 12              // anchor blocks (j) per WG
#define NBG 6              // anchor pairs per it-row
#define NIG 68             // ceil(GH/IT)
#define NJG 20             // GW/JT
#define TROWS (IT+8)       // 10 staged target block-rows
#define TBLK (JT+8)        // 20 staged target blocks per dy-row
#define DSTR (TBLK*64+4)   // 1284 dw: 16B-aligned; dr*1284 %32 = 4*dr (quad shift per row)
#define UNITS_ROW (TBLK*16)// 320 16B-units per dy-row
#define NTHR 256
#define NACT 216           // 9 dy * (2 it * 6 bg * 2 yh)
#define TT_DW (TROWS*DSTR) // 12840 dw = 51360 B -> 3 WG/CU (12 waves)
#define NWG (NIG*NJG)      // 1360 = 8*170 (XCD-exact)

// Swizzled storage (bijective involution, verified by example):
//   stored(blk, y, xh) = blk*64 + ((y*8+xh) ^ 4*kb ^ 16*yh),  kb=(blk>>1)&7, yh=y>>2
// - write side: lanes write LINEAR 16B units u (zero bank conflicts); global src
//   address is the inverse of the swizzle (m173/m201 both-sides-or-neither rule)
// - read side: quad = dr + 2*yi ^ kb ^ 4*yh -> 8-lane phase covers all 8 quads

// 8-px fp32 chain + f64 accumulate (argmin-exact vs np reference, proven r1-r4)
#define CHAIN(AV0, AV1, T0, T1, ACC) do { \
    float _d = (AV0).x - (T0).x; float _s = _d*_d; \
    _d = (AV0).y - (T0).y; _s = fmaf(_d,_d,_s); \
    _d = (AV0).z - (T0).z; _s = fmaf(_d,_d,_s); \
    _d = (AV0).w - (T0).w; _s = fmaf(_d,_d,_s); \
    _d = (AV1).x - (T1).x; _s = fmaf(_d,_d,_s); \
    _d = (AV1).y - (T1).y; _s = fmaf(_d,_d,_s); \
    _d = (AV1).z - (T1).z; _s = fmaf(_d,_d,_s); \
    _d = (AV1).w - (T1).w; _s = fmaf(_d,_d,_s); \
    (ACC) += (double)_s; } while(0)

__global__ void __launch_bounds__(NTHR, 3)
hbma_cost_kernel(const float* __restrict__ A, const float* __restrict__ T,
                 int* __restrict__ bestidx) {
    extern __shared__ float lds[];
    float* Tt = lds;

    // XCD swizzle: 1360 WGs = 8 XCDs x 170; per-XCD consecutive pos -> consecutive ig
    const int lin = blockIdx.x;
    const int g   = (lin & 7) * (NWG / 8) + (lin >> 3);
    const int ig  = g % NIG, jg = g / NIG;
    const int i0  = ig * IT;
    const int j0  = jg * JT;

    const int tid = threadIdx.x;
    const int dy  = tid / 24;          // 0..8
    const int rem = tid % 24;
    const int it  = rem / 12;          // 0..1
    const int r2  = rem % 12;
    const int bg  = r2 >> 1;           // 0..5 (anchor pair)
    const int yh  = r2 & 1;            // y-half
    const bool act = (tid < NACT);
    const int i   = i0 + it;
    const int gi  = i + dy - 4;
    const bool dyValid = act && (i < GH) && (gi >= 0) && (gi < GH);
    const int dr  = it + dy;           // staged row index 0..9

    int xq[5];                         // per p-pair h: 4*((bg+h)&7) ^ 16*yh
#pragma unroll
    for (int h = 0; h < 5; ++h) xq[h] = (((bg + h) & 7) * 4) ^ (yh << 4);

    double acc0[9], acc1[9];
#pragma unroll
    for (int d = 0; d < 9; ++d) { acc0[d] = 0.0; acc1[d] = 0.0; }

    const int gy0 = (i0 - 4) * 8;
    const int gx0 = (j0 - 4) * 8;

    for (int q = 0; q < NP; ++q) {
        const float* Tq = T + (size_t)q * HWPX;
        const float* Aq = A + (size_t)q * HWPX;
        __syncthreads();               // prev compute done before LDS overwrite
        // ---- stage target halo: LINEAR LDS writes, inverse-swizzled global src ----
        for (int w = tid; w < TROWS * UNITS_ROW; w += NTHR) {
            const int dyr = w / UNITS_ROW;
            const int u   = w - dyr * UNITS_ROW;    // 16B unit within dy-row
            const int blk = u >> 4, v = u & 15;
            const int kb  = (blk >> 1) & 7;
            const int yh2 = v >> 3;
            const int m3  = (v & 7) ^ kb ^ (yh2 << 2);
            const int y   = (yh2 << 2) + (m3 >> 1);
            const int xh4 = m3 & 1;
            const int gy  = gy0 + dyr * 8 + y;
            const int gx  = gx0 + blk * 8 + xh4 * 4;
            if ((unsigned)gy < (unsigned)HH && (unsigned)gx < (unsigned)WW) {
                *(float4*)(Tt + dyr * DSTR + u * 4) =
                    *(const float4*)(Tq + (size_t)gy * WW + gx);
            }
        }
        // ---- anchor rows -> registers (global; 9x dy-redundant -> L1-hot) ----
        float4 ar[2][4][2];
        if (act && i < GH) {
#pragma unroll
            for (int a2 = 0; a2 < 2; ++a2) {
                const float* ap = Aq + (size_t)(j0 + 2 * bg + a2) * 8;
#pragma unroll
                for (int yi = 0; yi < 4; ++yi) {
                    const float* row = ap + (size_t)(i * 8 + yh * 4 + yi) * WW;
                    ar[a2][yi][0] = *(const float4*)(row);
                    ar[a2][yi][1] = *(const float4*)(row + 4);
                }
            }
        }
        __syncthreads();
        // ---- SSD: sliding 10-block window serves 2 anchors x 9 dx ----
        if (dyValid) {
            const float* tb = Tt + dr * DSTR + bg * 128 + yh * 32;
#pragma unroll
            for (int yi = 0; yi < 4; ++yi) {
#pragma unroll
                for (int ph = 0; ph < 2; ++ph) {       // p-chunks of 5: 10-deep ds ILP
                    float4 tw0[5], tw1[5];
#pragma unroll
                    for (int pp = 0; pp < 5; ++pp) {
                        const int p  = ph * 5 + pp;
                        const int o0 = (yi * 8) ^ xq[p >> 1];
                        tw0[pp] = *(const float4*)(tb + p * 64 + o0);
                        tw1[pp] = *(const float4*)(tb + p * 64 + (o0 ^ 4));
                    }
#pragma unroll
                    for (int pp = 0; pp < 5; ++pp) {
                        const int p = ph * 5 + pp;
                        if (p < 9) CHAIN(ar[0][yi][0], ar[0][yi][1], tw0[pp], tw1[pp], acc0[p]);
                        if (p > 0) CHAIN(ar[1][yi][0], ar[1][yi][1], tw0[pp], tw1[pp], acc1[p - 1]);
                    }
                }
            }
        }
    }
    // ---- y-half merge via LDS (aliases Tt, barrier-protected) ----
    __syncthreads();
    double* yred = (double*)lds;                     // 108 pairs * 18 f64 = 3888 dw
    const int pairId = (it * NBG + bg) * 9 + dy;
    if (act && yh == 1) {
        double* d = yred + pairId * 18;
#pragma unroll
        for (int k = 0; k < 9; ++k) { d[k] = acc0[k]; d[9 + k] = acc1[k]; }
    }
    __syncthreads();
    double* redc = (double*)(lds + 8192);            // 216 f64 = 432 dw
    int*    redk = (int*)(lds + 8192 + 432);         // 216 int
    if (act && yh == 0) {
        const double* d = yred + pairId * 18;
#pragma unroll
        for (int k = 0; k < 9; ++k) { acc0[k] += d[k]; acc1[k] += d[9 + k]; }
        // stage-1 argmin over dx (ascending, strict < -> first-k ties)
#pragma unroll
        for (int a2 = 0; a2 < 2; ++a2) {
            double bc = 1e300; int bk = -1;
            const int jb = j0 + 2 * bg + a2;
#pragma unroll
            for (int dxi = 0; dxi < 9; ++dxi) {
                const int gj = jb + dxi - 4;
                const double c = a2 ? acc1[dxi] : acc0[dxi];
                if (dyValid && gj >= 0 && gj < GW && c < bc) { bc = c; bk = dy * 9 + dxi; }
            }
            redc[(it * 9 + dy) * JT + 2 * bg + a2] = bc;
            redk[(it * 9 + dy) * JT + 2 * bg + a2] = bk;
        }
    }
    __syncthreads();
    // ---- stage-2 argmin over dy (ascending, strict <) ----
    if (tid < IT * JT) {
        const int it2 = tid / JT, jt = tid % JT;
        if (i0 + it2 < GH) {
            double c = 1e300; int k = -1;
#pragma unroll
            for (int dyi = 0; dyi < 9; ++dyi) {
                const double v = redc[(it2 * 9 + dyi) * JT + jt];
                if (v < c) { c = v; k = redk[(it2 * 9 + dyi) * JT + jt]; }
            }
            const int dyi = k / 9, dxi = k % 9;
            const int bi = i0 + it2 + dyi - 4;
            const int bj = j0 + jt + dxi - 4;
            bestidx[(i0 + it2) * GW + j0 + jt] = (bi << 8) | bj;
        }
    }
}

__global__ void __launch_bounds__(256) hbma_gather_kernel(const float* __restrict__ A,
                                                          const int* __restrict__ bestidx,
                                                          float* __restrict__ out) {
    const int tid = blockIdx.x * 256 + threadIdx.x;
    const int q   = tid / (HWPX / 4);
    const int rem = tid % (HWPX / 4);
    const int py  = rem / (WW / 4);
    const int c4  = rem % (WW / 4);
    const int i = py >> 3, y = py & 7;
    const int j = c4 >> 1, xh = (c4 & 1) * 4;
    const int idx = bestidx[i * GW + j];
    const int bi = idx >> 8, bj = idx & 255;
    const float4 v = *(const float4*)(A + (size_t)q * HWPX + (size_t)(bi * 8 + y) * WW + bj * 8 + xh);
    *(float4*)(out + (size_t)q * HWPX + (size_t)py * WW + c4 * 4) = v;
}

extern "C" void kernel_launch(void* const* d_in, const int* in_sizes, int n_in,
                              void* d_out, int out_size, void* d_ws, size_t ws_size,
                              hipStream_t stream) {
    const float* A = (const float*)d_in[0];
    const float* T = (const float*)d_in[1];
    float* out = (float*)d_out;
    int* bestidx = (int*)d_ws;

    hipFuncSetAttribute((const void*)hbma_cost_kernel,
                        hipFuncAttributeMaxDynamicSharedMemorySize, TT_DW * 4);

    hipLaunchKernelGGL(hbma_cost_kernel, dim3(NWG), dim3(NTHR), TT_DW * 4, stream,
                       A, T, bestidx);

    const int total4 = (NP * HWPX) / 4;
    hipLaunchKernelGGL(hbma_gather_kernel, dim3(total4 / 256), dim3(256), 0, stream,
                       A, bestidx, out);
}